// Round 13
// baseline (205.479 us; speedup 1.0000x reference)
//
#include <hip/hip_runtime.h>

#define DIM   1024
#define BATCH 128
#define MAT   (BATCH*DIM)     // 131072
#define NROWS MAT
#define DS    32

typedef float f4n __attribute__((ext_vector_type(4)));

struct Params {
  const float *x,*Wq,*bq,*Wk,*bk,*Wv,*bv,*Wo,*bo,*W1,*b1,*W2,*b2;
  float *out,*nw;
  float *q,*k,*v,*araw,*x2,*h,*rinv,*P;
};

// ---------------------------------------------------------------------------
// Split-K partial GEMM tile (proven): tile 128b x 64n, KC steps of 32.
// ---------------------------------------------------------------------------
__device__ __forceinline__ void gemm_tile(
    const float* __restrict__ X, const float* __restrict__ W,
    float* __restrict__ Pout, int n0, int k0, int KC,
    float* xt, float* wt)
{
  const int tid = threadIdx.x;
  const int tn = tid & 15, tb = tid >> 4;
  const int b_base = tb*8, n_base = tn*4;
  float acc[8][4];
#pragma unroll
  for (int i=0;i<8;++i)
#pragma unroll
    for (int j=0;j<4;++j) acc[i][j]=0.f;

  for (int s=0; s<KC/DS; ++s) {
    const int kk = k0 + s*DS;
#pragma unroll
    for (int r=0;r<4;++r) {
      const int row = (tid>>3) + 32*r;
      const int c0  = (tid&7)*4;
      const float4 vv = *(const float4*)(X + (size_t)row*DIM + kk + c0);
      xt[(c0+0)*132+row]=vv.x; xt[(c0+1)*132+row]=vv.y;
      xt[(c0+2)*132+row]=vv.z; xt[(c0+3)*132+row]=vv.w;
    }
#pragma unroll
    for (int r=0;r<2;++r) {
      const int row = (tid>>3) + 32*r;
      const int c0  = (tid&7)*4;
      const f4n vv = __builtin_nontemporal_load(
          (const f4n*)(W + (size_t)(n0+row)*DIM + kk + c0));
      wt[(c0+0)*68+row]=vv.x; wt[(c0+1)*68+row]=vv.y;
      wt[(c0+2)*68+row]=vv.z; wt[(c0+3)*68+row]=vv.w;
    }
    __syncthreads();
#pragma unroll 4
    for (int d=0; d<DS; ++d) {
      const float4 xa0 = *(const float4*)&xt[d*132 + b_base];
      const float4 xa1 = *(const float4*)&xt[d*132 + b_base + 4];
      const float4 wa  = *(const float4*)&wt[d*68  + n_base];
      const float xr[8] = {xa0.x,xa0.y,xa0.z,xa0.w, xa1.x,xa1.y,xa1.z,xa1.w};
      const float wr[4] = {wa.x,wa.y,wa.z,wa.w};
#pragma unroll
      for (int bb=0;bb<8;++bb)
#pragma unroll
        for (int nn=0;nn<4;++nn) acc[bb][nn] += xr[bb]*wr[nn];
    }
    __syncthreads();
  }
#pragma unroll
  for (int bb=0;bb<8;++bb) {
    const float4 st = make_float4(acc[bb][0],acc[bb][1],acc[bb][2],acc[bb][3]);
    *(float4*)(Pout + (size_t)(b_base+bb)*DIM + n0 + n_base) = st;
  }
}

__global__ __launch_bounds__(256) void qkv_partial(
    const float* __restrict__ X, const float* __restrict__ W0,
    const float* __restrict__ W1, const float* __restrict__ W2,
    float* __restrict__ P)
{
  __shared__ float xt[DS*132];
  __shared__ float wt[DS*68];
  const int z = blockIdx.z;
  const float* W = (z==0)?W0:(z==1)?W1:W2;
  gemm_tile(X, W, P + (size_t)(z*8+blockIdx.y)*MAT,
            blockIdx.x*64, blockIdx.y*128, 128, xt, wt);
}

__global__ __launch_bounds__(256) void qkv_reduce(Params p)
{
  const int t = blockIdx.x*256 + threadIdx.x;     // 0..98303
  const int z = t >> 15, idx4 = t & 32767;
  const float4* Pz = (const float4*)(p.P + (size_t)z*8*MAT);
  const float*  bias = (z==0) ? p.bq : (z==1) ? p.bk : p.bv;
  float* outz = (z==0) ? p.q : (z==1) ? p.k : p.v;
  float4 s = Pz[idx4];
#pragma unroll
  for (int sp=1; sp<8; ++sp) {
    const float4 t2 = Pz[sp*(MAT/4)+idx4];
    s.x+=t2.x; s.y+=t2.y; s.z+=t2.z; s.w+=t2.w;
  }
  const float4 b4 = ((const float4*)bias)[idx4 & 255];
  s.x+=b4.x; s.y+=b4.y; s.z+=b4.z; s.w+=b4.w;
  ((float4*)outz)[idx4] = s;
}

// ---------------------------------------------------------------------------
// AR-only: 4096 waves x 32 consecutive rows (one batch per wave, k/v cached
// once). araw + rinv for ALL rows. No nw writes.
// ---------------------------------------------------------------------------
__global__ __launch_bounds__(256,4) void attn_ar(Params p)
{
  const int gw = blockIdx.x*4 + (threadIdx.x>>6);  // 0..4095
  const int lane = threadIdx.x & 63;
  const int b = gw >> 5;
  const float4* __restrict__ k4 = (const float4*)(p.k + ((size_t)b<<10));
  const float4* __restrict__ v4 = (const float4*)(p.v + ((size_t)b<<10));
  float4 kr[4], vr[4];
#pragma unroll
  for (int t=0;t<4;++t) { kr[t] = k4[lane + 64*t]; vr[t] = v4[lane + 64*t]; }
  const int r0 = gw*32;
#pragma unroll 1
  for (int r=0;r<32;++r) {
    const int row = r0 + r;
    const float c = p.q[row] * 0.03125f;
    float sum=0.f, dot=0.f;
#pragma unroll
    for (int t=0;t<4;++t) {
      const float ex=__expf(c*kr[t].x), ey=__expf(c*kr[t].y);
      const float ez=__expf(c*kr[t].z), ew=__expf(c*kr[t].w);
      sum += (ex+ey)+(ez+ew);
      dot += ex*vr[t].x + ey*vr[t].y + ez*vr[t].z + ew*vr[t].w;
    }
#pragma unroll
    for (int off=32; off>=1; off>>=1) {
      sum += __shfl_xor(sum, off);
      dot += __shfl_xor(dot, off);
    }
    const float rinv = 1.f/sum;
    if (lane==0) { p.araw[row] = dot*rinv; p.rinv[row] = rinv; }
  }
}

// pure split-16 GEMM dispatch (256 blocks)
__global__ __launch_bounds__(256) void gemmA(Params p,
    const float* __restrict__ X, const float* __restrict__ W)
{
  __shared__ float xt[DS*132];
  __shared__ float wt[DS*68];
  const int bid = blockIdx.x;
  gemm_tile(X, W, p.P + (size_t)(bid&15)*MAT, (bid>>4)*64, (bid&15)*64, 64, xt, wt);
}

// pure reduce+epilogue dispatch (128 blocks)
__global__ __launch_bounds__(256) void reduceB(Params p,
    const float* __restrict__ bias, const float* __restrict__ extra,
    float* __restrict__ out, int relu)
{
  const int idx4 = blockIdx.x*256 + threadIdx.x;
  const float4* P4 = (const float4*)p.P;
  float4 s = P4[idx4];
#pragma unroll
  for (int sp=1; sp<16; ++sp) {
    const float4 t2 = P4[sp*(MAT/4)+idx4];
    s.x+=t2.x; s.y+=t2.y; s.z+=t2.z; s.w+=t2.w;
  }
  const float4 b4 = ((const float4*)bias)[idx4 & 255];
  s.x+=b4.x; s.y+=b4.y; s.z+=b4.z; s.w+=b4.w;
  if (relu) { s.x=fmaxf(s.x,0.f); s.y=fmaxf(s.y,0.f);
              s.z=fmaxf(s.z,0.f); s.w=fmaxf(s.w,0.f); }
  if (extra) {
    const float4 e = ((const float4*)extra)[idx4];
    s.x+=e.x; s.y+=e.y; s.z+=e.z; s.w+=e.w;
  }
  ((float4*)out)[idx4] = s;
}

// ---------------------------------------------------------------------------
// PURE writer: 2048 blocks x 4 waves; wave g writes rows [g*16, g*16+16)
// (one batch per chunk -> k cached once). rinv precomputed -> no cross-lane
// ops. Plain stores (fill-style): each store instr covers 1KB contiguous.
// This dispatch owns the whole chip — measures the true softmax-writer BW.
// ---------------------------------------------------------------------------
__global__ __launch_bounds__(256,4) void big_writer(Params p)
{
  const int g = blockIdx.x*4 + (threadIdx.x>>6);   // 0..8191
  const int lane = threadIdx.x & 63;
  const int b = g >> 6;                            // 64 chunks per batch
  const float4* __restrict__ k4 = (const float4*)(p.k + ((size_t)b<<10));
  const float4 k0 = k4[lane], k1 = k4[lane+64], k2 = k4[lane+128], k3 = k4[lane+192];
  const int r0 = g*16;
#pragma unroll 1
  for (int r=0;r<16;++r) {
    const int row = r0 + r;
    const float c    = p.q[row] * 0.03125f;
    const float rinv = p.rinv[row];
    float4* o = (float4*)(p.nw + ((size_t)row<<10));
    float4 s0, s1, s2, s3;
    s0.x=__expf(c*k0.x)*rinv; s0.y=__expf(c*k0.y)*rinv;
    s0.z=__expf(c*k0.z)*rinv; s0.w=__expf(c*k0.w)*rinv;
    s1.x=__expf(c*k1.x)*rinv; s1.y=__expf(c*k1.y)*rinv;
    s1.z=__expf(c*k1.z)*rinv; s1.w=__expf(c*k1.w)*rinv;
    s2.x=__expf(c*k2.x)*rinv; s2.y=__expf(c*k2.y)*rinv;
    s2.z=__expf(c*k2.z)*rinv; s2.w=__expf(c*k2.w)*rinv;
    s3.x=__expf(c*k3.x)*rinv; s3.y=__expf(c*k3.y)*rinv;
    s3.z=__expf(c*k3.z)*rinv; s3.w=__expf(c*k3.w)*rinv;
    o[lane      ] = s0;
    o[lane +  64] = s1;
    o[lane + 128] = s2;
    o[lane + 192] = s3;
  }
}

// ---------------------------------------------------------------------------
extern "C" void kernel_launch(void* const* d_in, const int* in_sizes, int n_in,
                              void* d_out, int out_size, void* d_ws, size_t ws_size,
                              hipStream_t stream)
{
  (void)in_sizes; (void)n_in; (void)out_size; (void)ws_size;
  Params p;
  p.x  = (const float*)d_in[0];
  p.Wq = (const float*)d_in[1];  p.bq = (const float*)d_in[2];
  p.Wk = (const float*)d_in[3];  p.bk = (const float*)d_in[4];
  p.Wv = (const float*)d_in[5];  p.bv = (const float*)d_in[6];
  p.Wo = (const float*)d_in[7];  p.bo = (const float*)d_in[8];
  p.W1 = (const float*)d_in[9];  p.b1 = (const float*)d_in[10];
  p.W2 = (const float*)d_in[11]; p.b2 = (const float*)d_in[12];
  p.out = (float*)d_out;
  p.nw  = p.out + MAT;
  float* ws = (float*)d_ws;
  p.q    = ws;         p.k    = ws + MAT;   p.v = ws + 2*MAT;
  p.araw = ws + 3*MAT; p.x2   = ws + 4*MAT; p.h = ws + 5*MAT;
  p.rinv = ws + 6*MAT; p.P    = ws + 7*MAT;   // P: 24*MAT floats

  qkv_partial<<<dim3(16,8,3), 256, 0, stream>>>(p.x, p.Wq, p.Wk, p.Wv, p.P);
  qkv_reduce<<<384, 256, 0, stream>>>(p);

  attn_ar<<<1024, 256, 0, stream>>>(p);

  gemmA<<<256, 256, 0, stream>>>(p, p.araw, p.Wo);
  reduceB<<<128, 256, 0, stream>>>(p, p.bo, p.x, p.x2, 0);

  gemmA<<<256, 256, 0, stream>>>(p, p.x2, p.W1);
  reduceB<<<128, 256, 0, stream>>>(p, p.b1, nullptr, p.h, 1);

  gemmA<<<256, 256, 0, stream>>>(p, p.h, p.W2);
  reduceB<<<128, 256, 0, stream>>>(p, p.b2, p.x2, p.out, 0);

  big_writer<<<2048, 256, 0, stream>>>(p);
}

// Round 14
// 177.319 us; speedup vs baseline: 1.1588x; 1.1588x over previous
//
#include <hip/hip_runtime.h>

#define DIM   1024
#define BATCH 128
#define MAT   (BATCH*DIM)     // 131072
#define NROWS MAT
#define DS    32

typedef float f4n __attribute__((ext_vector_type(4)));  // native vec for nt builtins

// static nw-row quota bases (cumulative, exact partitions, no atomics)
#define Q_AT  28672            // attn dispatch writers: 1024 waves x 28
#define A_WO  28672            // chainA Wo: 3072 waves x 6 -> [28672,47104)
#define B_WO  47104            // chainB:    3584 waves x 2 -> [47104,54272)
#define A_W1  54272
#define B_W1  72704
#define A_W2  79872
#define B_W2  98304
#define MBASE 105472           // mopup: 25600 rows (1024 waves x7 + 3072 x6)

struct Params {
  const float *x,*Wq,*bq,*Wk,*bk,*Wv,*bv,*Wo,*bo,*W1,*b1,*W2,*b2;
  float *out,*nw;
  float *q,*k,*v,*araw,*x2,*h,*P;
};

// ---------------------------------------------------------------------------
// attn rows with k/v rows held in registers (16 VGPR each), reloaded only on
// batch change. nw stores are nontemporal (write-once data; keep L2 for k/W).
// Rank-1 scores: no max pass needed (|c*k| < ~0.3, exact softmax match).
// ---------------------------------------------------------------------------
template<bool WRITE, bool AR>
__device__ __forceinline__ void attn_range(const Params& p, int r0, int r1, int lane)
{
  int bcur = -1;
  float4 kr[4], vr[4];
#pragma unroll 1
  for (int row = r0; row < r1; ++row) {
    const int b = row >> 10;
    if (b != bcur) {
      bcur = b;
      const float4* __restrict__ k4 = (const float4*)(p.k + ((size_t)b<<10));
#pragma unroll
      for (int t=0;t<4;++t) kr[t] = k4[lane + 64*t];
      if (AR) {
        const float4* __restrict__ v4 = (const float4*)(p.v + ((size_t)b<<10));
#pragma unroll
        for (int t=0;t<4;++t) vr[t] = v4[lane + 64*t];
      }
    }
    const float c = p.q[row] * 0.03125f;
    float sum=0.f, dot=0.f;
    float4 e[4];
#pragma unroll
    for (int t=0;t<4;++t) {
      const float4 kk = kr[t];
      float4 pp;
      pp.x=__expf(c*kk.x); pp.y=__expf(c*kk.y);
      pp.z=__expf(c*kk.z); pp.w=__expf(c*kk.w);
      sum += (pp.x+pp.y)+(pp.z+pp.w);
      if (AR) {
        const float4 vv = vr[t];
        dot += pp.x*vv.x + pp.y*vv.y + pp.z*vv.z + pp.w*vv.w;
      }
      e[t]=pp;
    }
#pragma unroll
    for (int off=32; off>=1; off>>=1) {
      sum += __shfl_xor(sum, off);
      if (AR) dot += __shfl_xor(dot, off);
    }
    const float rinv = 1.f/sum;
    if (WRITE) {
      f4n* o = (f4n*)(p.nw + ((size_t)row<<10));
#pragma unroll
      for (int t=0;t<4;++t) {
        const float4 pp=e[t];
        f4n st;
        st.x = pp.x*rinv; st.y = pp.y*rinv;
        st.z = pp.z*rinv; st.w = pp.w*rinv;
        __builtin_nontemporal_store(st, &o[lane + 64*t]);
      }
    }
    if (AR && lane==0) p.araw[row] = dot*rinv;
  }
}

// ---------------------------------------------------------------------------
// Split-K partial GEMM tile: tile 128b x 64n, 256 threads, KC in steps of 32.
// W loads nontemporal (each W element read once). LDS transposed + padded.
// ---------------------------------------------------------------------------
__device__ __forceinline__ void gemm_tile(
    const float* __restrict__ X, const float* __restrict__ W,
    float* __restrict__ Pout, int n0, int k0, int KC,
    float* xt, float* wt)
{
  const int tid = threadIdx.x;
  const int tn = tid & 15, tb = tid >> 4;
  const int b_base = tb*8, n_base = tn*4;
  float acc[8][4];
#pragma unroll
  for (int i=0;i<8;++i)
#pragma unroll
    for (int j=0;j<4;++j) acc[i][j]=0.f;

  for (int s=0; s<KC/DS; ++s) {
    const int kk = k0 + s*DS;
#pragma unroll
    for (int r=0;r<4;++r) {
      const int row = (tid>>3) + 32*r;
      const int c0  = (tid&7)*4;
      const float4 vv = *(const float4*)(X + (size_t)row*DIM + kk + c0);
      xt[(c0+0)*132+row]=vv.x; xt[(c0+1)*132+row]=vv.y;
      xt[(c0+2)*132+row]=vv.z; xt[(c0+3)*132+row]=vv.w;
    }
#pragma unroll
    for (int r=0;r<2;++r) {
      const int row = (tid>>3) + 32*r;
      const int c0  = (tid&7)*4;
      const f4n vv = __builtin_nontemporal_load(
          (const f4n*)(W + (size_t)(n0+row)*DIM + kk + c0));
      wt[(c0+0)*68+row]=vv.x; wt[(c0+1)*68+row]=vv.y;
      wt[(c0+2)*68+row]=vv.z; wt[(c0+3)*68+row]=vv.w;
    }
    __syncthreads();
#pragma unroll 4
    for (int d=0; d<DS; ++d) {
      const float4 xa0 = *(const float4*)&xt[d*132 + b_base];
      const float4 xa1 = *(const float4*)&xt[d*132 + b_base + 4];
      const float4 wa  = *(const float4*)&wt[d*68  + n_base];
      const float xr[8] = {xa0.x,xa0.y,xa0.z,xa0.w, xa1.x,xa1.y,xa1.z,xa1.w};
      const float wr[4] = {wa.x,wa.y,wa.z,wa.w};
#pragma unroll
      for (int bb=0;bb<8;++bb)
#pragma unroll
        for (int nn=0;nn<4;++nn) acc[bb][nn] += xr[bb]*wr[nn];
    }
    __syncthreads();
  }
#pragma unroll
  for (int bb=0;bb<8;++bb) {
    const float4 st = make_float4(acc[bb][0],acc[bb][1],acc[bb][2],acc[bb][3]);
    *(float4*)(Pout + (size_t)(b_base+bb)*DIM + n0 + n_base) = st;
  }
}

// ---------------------------------------------------------------------------
__global__ __launch_bounds__(256) void qkv_partial(
    const float* __restrict__ X, const float* __restrict__ W0,
    const float* __restrict__ W1, const float* __restrict__ W2,
    float* __restrict__ P)
{
  __shared__ float xt[DS*132];
  __shared__ float wt[DS*68];
  const int z = blockIdx.z;
  const float* W = (z==0)?W0:(z==1)?W1:W2;
  gemm_tile(X, W, P + (size_t)(z*8+blockIdx.y)*MAT,
            blockIdx.x*64, blockIdx.y*128, 128, xt, wt);
}

__global__ __launch_bounds__(256) void qkv_reduce(Params p)
{
  const int t = blockIdx.x*256 + threadIdx.x;     // 0..98303
  const int z = t >> 15, idx4 = t & 32767;
  const float4* Pz = (const float4*)(p.P + (size_t)z*8*MAT);
  const float*  bias = (z==0) ? p.bq : (z==1) ? p.bk : p.bv;
  float* outz = (z==0) ? p.q : (z==1) ? p.k : p.v;
  float4 s = Pz[idx4];
#pragma unroll
  for (int sp=1; sp<8; ++sp) {
    const float4 t2 = Pz[sp*(MAT/4)+idx4];
    s.x+=t2.x; s.y+=t2.y; s.z+=t2.z; s.w+=t2.w;
  }
  const float4 b4 = ((const float4*)bias)[idx4 & 255];
  s.x+=b4.x; s.y+=b4.y; s.z+=b4.z; s.w+=b4.w;
  ((float4*)outz)[idx4] = s;
}

// ---------------------------------------------------------------------------
// attn: blocks 0..767 compute attn_raw for all rows (43/wave, AR only);
// blocks 768..1023 write nw rows [0, Q_AT) (28/wave).
// ---------------------------------------------------------------------------
__global__ __launch_bounds__(256,4) void attn_mixed(Params p)
{
  const int bid = blockIdx.x, tid = threadIdx.x;
  const int wave = tid>>6, lane = tid&63;
  if (bid < 768) {
    const int gw = bid*4 + wave;          // 0..3071
    int r0 = gw*43, r1 = r0 + 43;
    if (r1 > NROWS) r1 = NROWS;
    attn_range<false,true>(p, r0, r1, lane);
  } else {
    const int gw2 = (bid-768)*4 + wave;   // 0..1023
    attn_range<true,false>(p, gw2*28, gw2*28 + 28, lane);
  }
}

// ---------------------------------------------------------------------------
// chainA: blocks 0..255 = split-16 GEMM partials (K=64); 256..1023 = writers
// (3072 waves x 6 rows). chainB: 0..127 = reduce+epilogue; 128..1023 writers
// (3584 waves x 2 rows).
// ---------------------------------------------------------------------------
__global__ __launch_bounds__(256,4) void chainA(Params p,
    const float* __restrict__ X, const float* __restrict__ W, int wbase)
{
  __shared__ float xt[DS*132];
  __shared__ float wt[DS*68];
  const int bid = blockIdx.x, tid = threadIdx.x;
  const int wave = tid>>6, lane = tid&63;
  if (bid < 256) {
    gemm_tile(X, W, p.P + (size_t)(bid&15)*MAT, (bid>>4)*64, (bid&15)*64, 64, xt, wt);
  } else {
    const int gw = (bid-256)*4 + wave;    // 0..3071
    attn_range<true,false>(p, wbase + gw*6, wbase + gw*6 + 6, lane);
  }
}

__global__ __launch_bounds__(256,4) void chainB(Params p,
    const float* __restrict__ bias, const float* __restrict__ extra,
    float* __restrict__ out, int relu, int wbase)
{
  const int bid = blockIdx.x, tid = threadIdx.x;
  const int wave = tid>>6, lane = tid&63;
  if (bid < 128) {
    const int idx4 = bid*256 + tid;
    const float4* P4 = (const float4*)p.P;
    float4 s = P4[idx4];
#pragma unroll
    for (int sp=1; sp<16; ++sp) {
      const float4 t2 = P4[sp*(MAT/4)+idx4];
      s.x+=t2.x; s.y+=t2.y; s.z+=t2.z; s.w+=t2.w;
    }
    const float4 b4 = ((const float4*)bias)[idx4 & 255];
    s.x+=b4.x; s.y+=b4.y; s.z+=b4.z; s.w+=b4.w;
    if (relu) { s.x=fmaxf(s.x,0.f); s.y=fmaxf(s.y,0.f);
                s.z=fmaxf(s.z,0.f); s.w=fmaxf(s.w,0.f); }
    if (extra) {
      const float4 e = ((const float4*)extra)[idx4];
      s.x+=e.x; s.y+=e.y; s.z+=e.z; s.w+=e.w;
    }
    ((float4*)out)[idx4] = s;
  } else {
    const int gw = (bid-128)*4 + wave;    // 0..3583
    attn_range<true,false>(p, wbase + gw*2, wbase + gw*2 + 2, lane);
  }
}

// mopup: 4096 waves cover remaining 25600 rows (1024 x 7, 3072 x 6)
__global__ __launch_bounds__(256,4) void mopup(Params p)
{
  const int gw = blockIdx.x*4 + (threadIdx.x>>6);
  const int lane = threadIdx.x & 63;
  int r0, n;
  if (gw < 1024) { r0 = MBASE + gw*7;             n = 7; }
  else           { r0 = MBASE + 7168 + (gw-1024)*6; n = 6; }
  attn_range<true,false>(p, r0, r0 + n, lane);
}

// ---------------------------------------------------------------------------
extern "C" void kernel_launch(void* const* d_in, const int* in_sizes, int n_in,
                              void* d_out, int out_size, void* d_ws, size_t ws_size,
                              hipStream_t stream)
{
  (void)in_sizes; (void)n_in; (void)out_size; (void)ws_size;
  Params p;
  p.x  = (const float*)d_in[0];
  p.Wq = (const float*)d_in[1];  p.bq = (const float*)d_in[2];
  p.Wk = (const float*)d_in[3];  p.bk = (const float*)d_in[4];
  p.Wv = (const float*)d_in[5];  p.bv = (const float*)d_in[6];
  p.Wo = (const float*)d_in[7];  p.bo = (const float*)d_in[8];
  p.W1 = (const float*)d_in[9];  p.b1 = (const float*)d_in[10];
  p.W2 = (const float*)d_in[11]; p.b2 = (const float*)d_in[12];
  p.out = (float*)d_out;
  p.nw  = p.out + MAT;
  float* ws = (float*)d_ws;
  p.q    = ws;         p.k  = ws + MAT;   p.v = ws + 2*MAT;
  p.araw = ws + 3*MAT; p.x2 = ws + 4*MAT; p.h = ws + 5*MAT;
  p.P    = ws + 6*MAT;

  qkv_partial<<<dim3(16,8,3), 256, 0, stream>>>(p.x, p.Wq, p.Wk, p.Wv, p.P);
  qkv_reduce<<<384, 256, 0, stream>>>(p);

  attn_mixed<<<1024, 256, 0, stream>>>(p);

  chainA<<<1024, 256, 0, stream>>>(p, p.araw, p.Wo, A_WO);
  chainB<<<1024, 256, 0, stream>>>(p, p.bo, p.x, p.x2, 0, B_WO);

  chainA<<<1024, 256, 0, stream>>>(p, p.x2, p.W1, A_W1);
  chainB<<<1024, 256, 0, stream>>>(p, p.b1, nullptr, p.h, 1, B_W1);

  chainA<<<1024, 256, 0, stream>>>(p, p.h, p.W2, A_W2);
  chainB<<<1024, 256, 0, stream>>>(p, p.b2, p.x2, p.out, 0, B_W2);

  mopup<<<1024, 256, 0, stream>>>(p);
}